// Round 1
// baseline (34649.615 us; speedup 1.0000x reference)
//
#include <hip/hip_runtime.h>

// FHN Neural ODE: 19999 RK4(3/8) steps of a 2-64-64-2 tanh MLP.
// Strictly sequential across steps -> single wave64, lane i = hidden neuron i.
// All weights register-resident; h1 broadcast via v_readlane (SGPR FMA operand);
// output reduction via 6-hop butterfly shuffle (bit-identical across lanes, so
// the state y stays wave-uniform).

__device__ __forceinline__ float fast_tanh(float x) {
    // tanh(x) = 1 - 2/(exp(2x)+1); exact at +-inf saturation, ~1e-7 rel error.
    float e = __expf(2.0f * x);
    float r = __builtin_amdgcn_rcpf(e + 1.0f);
    return fmaf(-2.0f, r, 1.0f);
}

struct Weights {
    float w1a, w1b, b1v, b2v, w3a, w3b, b3a, b3b;
};

__device__ __forceinline__ void mlp_eval(float y0, float y1, const Weights& w,
                                         const float (&w2)[64],
                                         float& o0, float& o1)
{
    // layer 1: per-lane, y is wave-uniform
    float h1 = fast_tanh(fmaf(w.w1a, y0, fmaf(w.w1b, y1, w.b1v)));
    int hb = __float_as_int(h1);

    // layer 2: dot(W2 row, h1) with h1[j] broadcast via readlane -> SGPR
    float a0 = w.b2v, a1 = 0.0f, a2 = 0.0f, a3 = 0.0f;
#pragma unroll
    for (int j = 0; j < 64; j += 4) {
        a0 = fmaf(w2[j + 0], __int_as_float(__builtin_amdgcn_readlane(hb, j + 0)), a0);
        a1 = fmaf(w2[j + 1], __int_as_float(__builtin_amdgcn_readlane(hb, j + 1)), a1);
        a2 = fmaf(w2[j + 2], __int_as_float(__builtin_amdgcn_readlane(hb, j + 2)), a2);
        a3 = fmaf(w2[j + 3], __int_as_float(__builtin_amdgcn_readlane(hb, j + 3)), a3);
    }
    float h2 = fast_tanh((a0 + a1) + (a2 + a3));

    // layer 3: two 64-lane butterfly reductions (results uniform across lanes)
    float p0 = w.w3a * h2;
    float p1 = w.w3b * h2;
#pragma unroll
    for (int m = 1; m < 64; m <<= 1) {
        p0 += __shfl_xor(p0, m, 64);
        p1 += __shfl_xor(p1, m, 64);
    }
    o0 = p0 + w.b3a;
    o1 = p1 + w.b3b;
}

extern "C" __global__ void __launch_bounds__(64, 1)
fhn_ode_kernel(const float* __restrict__ t,
               const float* __restrict__ v0,
               const float* __restrict__ W1, const float* __restrict__ b1,
               const float* __restrict__ W2, const float* __restrict__ b2,
               const float* __restrict__ W3, const float* __restrict__ b3,
               const float* __restrict__ w0,
               float* __restrict__ out, int T)
{
    const int lane = threadIdx.x;

    Weights w;
    w.w1a = W1[2 * lane];
    w.w1b = W1[2 * lane + 1];
    w.b1v = b1[lane];
    w.b2v = b2[lane];
    w.w3a = W3[lane];
    w.w3b = W3[64 + lane];
    w.b3a = b3[0];
    w.b3b = b3[1];

    // W2 row i -> 64 registers per lane (16 KB total in the RF)
    float w2[64];
#pragma unroll
    for (int j = 0; j < 16; ++j) {
        float4 v = reinterpret_cast<const float4*>(W2 + 64 * lane)[j];
        w2[4 * j + 0] = v.x;
        w2[4 * j + 1] = v.y;
        w2[4 * j + 2] = v.z;
        w2[4 * j + 3] = v.w;
    }

    float y0 = v0[0];
    float y1 = w0[0];
    if (lane == 0) {
        out[0] = y0;
        out[1] = y1;
    }

    const float third = 1.0f / 3.0f;
    float tc = t[0];
    float tn = t[1];

    for (int i = 1; i < T; ++i) {
        float dt = tn - tc;
        tc = tn;
        int nx = (i + 1 < T) ? (i + 1) : i;
        tn = t[nx];  // uniform s_load, consumed next iteration (latency hidden)

        float k1x, k1y, k2x, k2y, k3x, k3y, k4x, k4y;
        mlp_eval(y0, y1, w, w2, k1x, k1y);
        mlp_eval(y0 + dt * k1x * third,
                 y1 + dt * k1y * third, w, w2, k2x, k2y);
        mlp_eval(y0 + dt * (k2x - k1x * third),
                 y1 + dt * (k2y - k1y * third), w, w2, k3x, k3y);
        mlp_eval(y0 + dt * (k1x - k2x + k3x),
                 y1 + dt * (k1y - k2y + k3y), w, w2, k4x, k4y);

        float s = dt * 0.125f;
        y0 = y0 + (k1x + 3.0f * (k2x + k3x) + k4x) * s;
        y1 = y1 + (k1y + 3.0f * (k2y + k3y) + k4y) * s;

        if (lane == 0) {
            out[2 * i]     = y0;
            out[2 * i + 1] = y1;
        }
    }
}

extern "C" void kernel_launch(void* const* d_in, const int* in_sizes, int n_in,
                              void* d_out, int out_size, void* d_ws, size_t ws_size,
                              hipStream_t stream) {
    const float* t  = (const float*)d_in[0];
    const float* v0 = (const float*)d_in[1];
    const float* W1 = (const float*)d_in[2];
    const float* b1 = (const float*)d_in[3];
    const float* W2 = (const float*)d_in[4];
    const float* b2 = (const float*)d_in[5];
    const float* W3 = (const float*)d_in[6];
    const float* b3 = (const float*)d_in[7];
    const float* w0 = (const float*)d_in[8];
    float* out = (float*)d_out;
    int T = in_sizes[0];

    hipLaunchKernelGGL(fhn_ode_kernel, dim3(1), dim3(64), 0, stream,
                       t, v0, W1, b1, W2, b2, W3, b3, w0, out, T);
}

// Round 2
// 29166.571 us; speedup vs baseline: 1.1880x; 1.1880x over previous
//
#include <hip/hip_runtime.h>

// FHN Neural ODE: 19999 RK4(3/8) steps of a 2-64-64-2 tanh MLP.
// Strictly sequential across steps -> single wave64, lane i = hidden neuron i.
// R1 changes:
//  - W2 row pinned in 64 VGPRs via empty inline-asm (R0 showed VGPR_Count=48:
//    compiler was re-loading W2 from memory inside every eval).
//  - Layer-3 reduction via DPP (row_shr 1/2/4/8 + row_bcast 15/31 + readlane 63)
//    instead of ds_swizzle butterfly: VALU-latency cross-lane, result in SGPR.

__device__ __forceinline__ float fast_tanh(float x) {
    // tanh(x) = 1 - 2/(exp(2x)+1)
    float e = __expf(2.0f * x);
    float r = __builtin_amdgcn_rcpf(e + 1.0f);
    return fmaf(-2.0f, r, 1.0f);
}

template <int CTRL>
__device__ __forceinline__ float dpp_add(float x) {
    int t = __builtin_amdgcn_update_dpp(0, __float_as_int(x), CTRL, 0xf, 0xf, false);
    return x + __int_as_float(t);
}

// Full-wave64 sum; total lands in lane 63, returned as a wave-uniform SGPR value.
__device__ __forceinline__ float wave_sum_uniform(float x) {
    x = dpp_add<0x111>(x);  // row_shr:1
    x = dpp_add<0x112>(x);  // row_shr:2
    x = dpp_add<0x114>(x);  // row_shr:4
    x = dpp_add<0x118>(x);  // row_shr:8
    x = dpp_add<0x142>(x);  // row_bcast:15
    x = dpp_add<0x143>(x);  // row_bcast:31
    return __int_as_float(__builtin_amdgcn_readlane(__float_as_int(x), 63));
}

struct Weights {
    float w1a, w1b, b1v, b2v, w3a, w3b, b3a, b3b;
};

__device__ __forceinline__ void mlp_eval(float y0, float y1, const Weights& w,
                                         const float (&w2)[64],
                                         float& o0, float& o1)
{
    // layer 1: per-lane, y is wave-uniform
    float h1 = fast_tanh(fmaf(w.w1a, y0, fmaf(w.w1b, y1, w.b1v)));
    int hb = __float_as_int(h1);

    // layer 2: dot(W2 row, h1); h1[j] broadcast via readlane -> SGPR FMA operand.
    // 4 independent accumulator chains to cover VALU latency.
    float a0 = w.b2v, a1 = 0.0f, a2 = 0.0f, a3 = 0.0f;
#pragma unroll
    for (int j = 0; j < 64; j += 4) {
        a0 = fmaf(w2[j + 0], __int_as_float(__builtin_amdgcn_readlane(hb, j + 0)), a0);
        a1 = fmaf(w2[j + 1], __int_as_float(__builtin_amdgcn_readlane(hb, j + 1)), a1);
        a2 = fmaf(w2[j + 2], __int_as_float(__builtin_amdgcn_readlane(hb, j + 2)), a2);
        a3 = fmaf(w2[j + 3], __int_as_float(__builtin_amdgcn_readlane(hb, j + 3)), a3);
    }
    float h2 = fast_tanh((a0 + a1) + (a2 + a3));

    // layer 3: two DPP wave-reductions (independent chains interleave)
    o0 = wave_sum_uniform(w.w3a * h2) + w.b3a;
    o1 = wave_sum_uniform(w.w3b * h2) + w.b3b;
}

extern "C" __global__ void __launch_bounds__(64, 1)
fhn_ode_kernel(const float* __restrict__ t,
               const float* __restrict__ v0,
               const float* __restrict__ W1, const float* __restrict__ b1,
               const float* __restrict__ W2, const float* __restrict__ b2,
               const float* __restrict__ W3, const float* __restrict__ b3,
               const float* __restrict__ w0,
               float* __restrict__ out, int T)
{
    const int lane = threadIdx.x;

    Weights w;
    w.w1a = W1[2 * lane];
    w.w1b = W1[2 * lane + 1];
    w.b1v = b1[lane];
    w.b2v = b2[lane];
    w.w3a = W3[lane];
    w.w3b = W3[64 + lane];
    w.b3a = b3[0];
    w.b3b = b3[1];

    // W2 row i -> 64 VGPRs per lane (16 KB total in RF).
    float w2[64];
#pragma unroll
    for (int j = 0; j < 16; ++j) {
        float4 v = reinterpret_cast<const float4*>(W2 + 64 * lane)[j];
        w2[4 * j + 0] = v.x;
        w2[4 * j + 1] = v.y;
        w2[4 * j + 2] = v.z;
        w2[4 * j + 3] = v.w;
    }
    // Pin: make values opaque so the compiler cannot rematerialize the loads
    // inside the step loop (R0 evidence: VGPR_Count=48 -> W2 was being re-read
    // from memory in every eval).
#pragma unroll
    for (int j = 0; j < 64; j += 4) {
        asm volatile("" : "+v"(w2[j]), "+v"(w2[j + 1]), "+v"(w2[j + 2]), "+v"(w2[j + 3]));
    }

    float y0 = v0[0];
    float y1 = w0[0];
    if (lane == 0) {
        out[0] = y0;
        out[1] = y1;
    }

    const float third = 1.0f / 3.0f;
    float tc = t[0];
    float tn = t[1];

    for (int i = 1; i < T; ++i) {
        float dt = tn - tc;
        tc = tn;
        int nx = (i + 1 < T) ? (i + 1) : i;
        tn = t[nx];  // uniform s_load, consumed next iteration (latency hidden)

        float k1x, k1y, k2x, k2y, k3x, k3y, k4x, k4y;
        mlp_eval(y0, y1, w, w2, k1x, k1y);
        mlp_eval(y0 + dt * k1x * third,
                 y1 + dt * k1y * third, w, w2, k2x, k2y);
        mlp_eval(y0 + dt * (k2x - k1x * third),
                 y1 + dt * (k2y - k1y * third), w, w2, k3x, k3y);
        mlp_eval(y0 + dt * (k1x - k2x + k3x),
                 y1 + dt * (k1y - k2y + k3y), w, w2, k4x, k4y);

        float s = dt * 0.125f;
        y0 = y0 + (k1x + 3.0f * (k2x + k3x) + k4x) * s;
        y1 = y1 + (k1y + 3.0f * (k2y + k3y) + k4y) * s;

        if (lane == 0) {
            out[2 * i]     = y0;
            out[2 * i + 1] = y1;
        }
    }
}

extern "C" void kernel_launch(void* const* d_in, const int* in_sizes, int n_in,
                              void* d_out, int out_size, void* d_ws, size_t ws_size,
                              hipStream_t stream) {
    const float* t  = (const float*)d_in[0];
    const float* v0 = (const float*)d_in[1];
    const float* W1 = (const float*)d_in[2];
    const float* b1 = (const float*)d_in[3];
    const float* W2 = (const float*)d_in[4];
    const float* b2 = (const float*)d_in[5];
    const float* W3 = (const float*)d_in[6];
    const float* b3 = (const float*)d_in[7];
    const float* w0 = (const float*)d_in[8];
    float* out = (float*)d_out;
    int T = in_sizes[0];

    hipLaunchKernelGGL(fhn_ode_kernel, dim3(1), dim3(64), 0, stream,
                       t, v0, W1, b1, W2, b2, W3, b3, w0, out, T);
}

// Round 3
// 29158.856 us; speedup vs baseline: 1.1883x; 1.0003x over previous
//
#include <hip/hip_runtime.h>

// FHN Neural ODE: 19999 RK4(3/8) steps of a 2-64-64-2 tanh MLP.
// Single wave64, lane i = hidden neuron i.
// R2: W2 row held in 64 INDIVIDUALLY NAMED scalars + macro-generated
// straight-line layer-2 (R0/R1 evidence: VGPR_Count=44/48 -> the w2[64]
// array was demoted to scratch because the readlane loop wasn't fully
// unrolled; per-eval scratch reloads dominated the critical path).

__device__ __forceinline__ float fast_tanh(float x) {
    // tanh(x) = 1 - 2/(exp(2x)+1)
    float e = __expf(2.0f * x);
    float r = __builtin_amdgcn_rcpf(e + 1.0f);
    return fmaf(-2.0f, r, 1.0f);
}

template <int CTRL>
__device__ __forceinline__ float dpp_add(float x) {
    int t = __builtin_amdgcn_update_dpp(0, __float_as_int(x), CTRL, 0xf, 0xf, false);
    return x + __int_as_float(t);
}

// Full-wave64 sum; total lands in lane 63, returned wave-uniform via readlane.
__device__ __forceinline__ float wave_sum_uniform(float x) {
    x = dpp_add<0x111>(x);  // row_shr:1
    x = dpp_add<0x112>(x);  // row_shr:2
    x = dpp_add<0x114>(x);  // row_shr:4
    x = dpp_add<0x118>(x);  // row_shr:8
    x = dpp_add<0x142>(x);  // row_bcast:15
    x = dpp_add<0x143>(x);  // row_bcast:31
    return __int_as_float(__builtin_amdgcn_readlane(__float_as_int(x), 63));
}

// Apply macro M(a,b,c,d,group) over all 16 groups of 4 indices.
#define ALL_GROUPS(M) \
    M(0,1,2,3,0)     M(4,5,6,7,1)     M(8,9,10,11,2)   M(12,13,14,15,3)  \
    M(16,17,18,19,4) M(20,21,22,23,5) M(24,25,26,27,6) M(28,29,30,31,7)  \
    M(32,33,34,35,8) M(36,37,38,39,9) M(40,41,42,43,10) M(44,45,46,47,11) \
    M(48,49,50,51,12) M(52,53,54,55,13) M(56,57,58,59,14) M(60,61,62,63,15)

#define DECLG(a,b,c,d,g) float w2_##a, w2_##b, w2_##c, w2_##d;
#define LOADG(a,b,c,d,g) { float4 v = w2vec[g]; \
    w2_##a = v.x; w2_##b = v.y; w2_##c = v.z; w2_##d = v.w; }
#define PING(a,b,c,d,g) \
    asm volatile("" : "+v"(w2_##a), "+v"(w2_##b), "+v"(w2_##c), "+v"(w2_##d));
// 4 independent accumulator chains; readlane lane index is a literal.
#define L2G(a,b,c,d,g) \
    acc0 = fmaf(w2_##a, __int_as_float(__builtin_amdgcn_readlane(hb, a)), acc0); \
    acc1 = fmaf(w2_##b, __int_as_float(__builtin_amdgcn_readlane(hb, b)), acc1); \
    acc2 = fmaf(w2_##c, __int_as_float(__builtin_amdgcn_readlane(hb, c)), acc2); \
    acc3 = fmaf(w2_##d, __int_as_float(__builtin_amdgcn_readlane(hb, d)), acc3);

extern "C" __global__ void __launch_bounds__(64, 1)
fhn_ode_kernel(const float* __restrict__ t,
               const float* __restrict__ v0,
               const float* __restrict__ W1, const float* __restrict__ b1,
               const float* __restrict__ W2, const float* __restrict__ b2,
               const float* __restrict__ W3, const float* __restrict__ b3,
               const float* __restrict__ w0,
               float* __restrict__ out, int T)
{
    const int lane = threadIdx.x;

    const float w1a = W1[2 * lane];
    const float w1b = W1[2 * lane + 1];
    const float b1v = b1[lane];
    const float b2v = b2[lane];
    const float w3a = W3[lane];
    const float w3b = W3[64 + lane];
    const float b3a = b3[0];
    const float b3b = b3[1];

    // W2 row i -> 64 named scalars (64 VGPRs/lane, 16 KB total in RF).
    const float4* w2vec = reinterpret_cast<const float4*>(W2 + 64 * lane);
    ALL_GROUPS(DECLG)
    ALL_GROUPS(LOADG)
    ALL_GROUPS(PING)   // opacify so the loads can't be sunk into the loop

    // One MLP eval; y is wave-uniform, outputs are wave-uniform.
    auto mlp_eval = [&](float y0v, float y1v, float& o0, float& o1) {
        float h1 = fast_tanh(fmaf(w1a, y0v, fmaf(w1b, y1v, b1v)));
        int hb = __float_as_int(h1);
        float acc0 = b2v, acc1 = 0.0f, acc2 = 0.0f, acc3 = 0.0f;
        ALL_GROUPS(L2G)
        float h2 = fast_tanh((acc0 + acc1) + (acc2 + acc3));
        o0 = wave_sum_uniform(w3a * h2) + b3a;
        o1 = wave_sum_uniform(w3b * h2) + b3b;
    };

    float y0 = v0[0];
    float y1 = w0[0];
    if (lane == 0) {
        reinterpret_cast<float2*>(out)[0] = make_float2(y0, y1);
    }

    const float third = 1.0f / 3.0f;
    float tc = t[0];
    float tn = t[1];

    for (int i = 1; i < T; ++i) {
        float dt = tn - tc;
        tc = tn;
        int nx = (i + 1 < T) ? (i + 1) : i;
        tn = t[nx];  // uniform load, consumed next iteration (latency hidden)

        float k1x, k1y, k2x, k2y, k3x, k3y, k4x, k4y;
        mlp_eval(y0, y1, k1x, k1y);
        mlp_eval(y0 + dt * k1x * third,
                 y1 + dt * k1y * third, k2x, k2y);
        mlp_eval(y0 + dt * (k2x - k1x * third),
                 y1 + dt * (k2y - k1y * third), k3x, k3y);
        mlp_eval(y0 + dt * (k1x - k2x + k3x),
                 y1 + dt * (k1y - k2y + k3y), k4x, k4y);

        float s = dt * 0.125f;
        y0 = y0 + (k1x + 3.0f * (k2x + k3x) + k4x) * s;
        y1 = y1 + (k1y + 3.0f * (k2y + k3y) + k4y) * s;

        if (lane == 0) {
            reinterpret_cast<float2*>(out)[i] = make_float2(y0, y1);
        }
    }
}

extern "C" void kernel_launch(void* const* d_in, const int* in_sizes, int n_in,
                              void* d_out, int out_size, void* d_ws, size_t ws_size,
                              hipStream_t stream) {
    const float* t  = (const float*)d_in[0];
    const float* v0 = (const float*)d_in[1];
    const float* W1 = (const float*)d_in[2];
    const float* b1 = (const float*)d_in[3];
    const float* W2 = (const float*)d_in[4];
    const float* b2 = (const float*)d_in[5];
    const float* W3 = (const float*)d_in[6];
    const float* b3 = (const float*)d_in[7];
    const float* w0 = (const float*)d_in[8];
    float* out = (float*)d_out;
    int T = in_sizes[0];

    hipLaunchKernelGGL(fhn_ode_kernel, dim3(1), dim3(64), 0, stream,
                       t, v0, W1, b1, W2, b2, W3, b3, w0, out, T);
}